// Round 4
// baseline (2233.974 us; speedup 1.0000x reference)
//
#include <hip/hip_runtime.h>

typedef unsigned short ushort_t;
typedef unsigned int uint_t;

using f16x8 = __attribute__((ext_vector_type(8))) _Float16;
using f16x2 = __attribute__((ext_vector_type(2))) _Float16;
using f32x4 = __attribute__((ext_vector_type(4))) float;

#define BATCH 64
#define SEQT 512
#define DIN 256
#define HID 256
#define G4 1024   // 4*HID

#define RCH 24    // U k-chunks held in registers (per column)
#define LCH 8     // U k-chunks held in LDS

// Opaque value barrier: compiler cannot rematerialize these from memory.
#define PIN4(v) asm volatile("" : "+v"((v).x), "+v"((v).y), "+v"((v).z), "+v"((v).w))

static __device__ __forceinline__ ushort_t f16b(float x) {
    return __builtin_bit_cast(ushort_t, (_Float16)x);
}
static __device__ __forceinline__ uint_t pk2(float a, float b) {
    return (uint_t)f16b(a) | ((uint_t)f16b(b) << 16);
}
static __device__ __forceinline__ float sig_(float x) {
    return 1.f / (1.f + __expf(-x));
}
static __device__ __forceinline__ float tanh_(float x) {
    float e = __expf(2.f * x);
    return (e - 1.f) / (e + 1.f);
}

// z += dot(u, h) over 8 f16 values
static __device__ __forceinline__ void dot8(float& z, const uint4& u, const uint4& h) {
    const uint_t* up = &u.x;
    const uint_t* hp = &h.x;
#pragma unroll
    for (int q = 0; q < 4; ++q) {
        f16x2 hv = __builtin_bit_cast(f16x2, hp[q]);
        f16x2 uv = __builtin_bit_cast(f16x2, up[q]);
#if __has_builtin(__builtin_amdgcn_fdot2)
        z = __builtin_amdgcn_fdot2(hv, uv, z, false);
#else
        z += (float)hv.x * (float)uv.x + (float)hv.y * (float)uv.y;
#endif
    }
}

// ---------------- prep kernels ----------------

__global__ void cvt_x_kernel(const float* __restrict__ in, ushort_t* __restrict__ out, int n4) {
    int i = blockIdx.x * blockDim.x + threadIdx.x;
    if (i < n4) {
        float4 v = ((const float4*)in)[i];
        ushort4 o;
        o.x = f16b(v.x); o.y = f16b(v.y); o.z = f16b(v.z); o.w = f16b(v.w);
        ((ushort4*)out)[i] = o;
    }
}

// W [256][1024] f32 -> Wt [1024][256] f16 bits (transpose)
__global__ void prep_wt_kernel(const float* __restrict__ W, ushort_t* __restrict__ Wt) {
    int tid = blockIdx.x * blockDim.x + threadIdx.x;
    int k = tid >> 10;
    int n = tid & 1023;
    Wt[n * DIN + k] = f16b(W[tid]);
}

// U [256][1024] f32 -> Upk [32][1024] uint4
__global__ void prep_upk_kernel(const float* __restrict__ U, uint4* __restrict__ Upk) {
    int tid = blockIdx.x * blockDim.x + threadIdx.x;
    int j = tid >> 10;
    int g = tid & 1023;
    uint4 o;
    uint_t* op = &o.x;
#pragma unroll
    for (int q = 0; q < 4; ++q) {
        float a = U[(8 * j + 2 * q) * G4 + g];
        float b = U[(8 * j + 2 * q + 1) * G4 + g];
        op[q] = pk2(a, b);
    }
    Upk[tid] = o;
}

// ---------------- GEMM ----------------

#define GSTRIDE 40

__global__ __launch_bounds__(256) void gemm_f16_kernel(
    const ushort_t* __restrict__ A,
    const ushort_t* __restrict__ Bt,
    const float* __restrict__ bias,
    float* __restrict__ C,
    int M)
{
    const int K = DIN, N = G4;
    __shared__ ushort_t As[128 * GSTRIDE];
    __shared__ ushort_t Bs[128 * GSTRIDE];
    int tid = threadIdx.x;
    int bx = blockIdx.x & 7;
    int by = blockIdx.x >> 3;
    int m0 = by * 128, n0 = bx * 128;
    int w = tid >> 6, lane = tid & 63;
    int wr = (w >> 1) * 64, wc = (w & 1) * 64;
    int r = lane & 15, kg = lane >> 4;

    f32x4 acc[4][4];
#pragma unroll
    for (int i = 0; i < 4; ++i)
#pragma unroll
        for (int j = 0; j < 4; ++j)
            acc[i][j] = f32x4{0.f, 0.f, 0.f, 0.f};

    for (int kt = 0; kt < K; kt += 32) {
        __syncthreads();
#pragma unroll
        for (int s = 0; s < 2; ++s) {
            int chunk = tid + s * 256;
            int row = chunk >> 2;
            int ko = (chunk & 3) * 8;
            uint4 va = *(const uint4*)(A + (size_t)(m0 + row) * K + kt + ko);
            *(uint4*)(&As[row * GSTRIDE + ko]) = va;
            uint4 vb = *(const uint4*)(Bt + (size_t)(n0 + row) * K + kt + ko);
            *(uint4*)(&Bs[row * GSTRIDE + ko]) = vb;
        }
        __syncthreads();
        f16x8 af[4], bf[4];
#pragma unroll
        for (int i = 0; i < 4; ++i) {
            af[i] = *(const f16x8*)(&As[(wr + i * 16 + r) * GSTRIDE + kg * 8]);
            bf[i] = *(const f16x8*)(&Bs[(wc + i * 16 + r) * GSTRIDE + kg * 8]);
        }
#pragma unroll
        for (int i = 0; i < 4; ++i)
#pragma unroll
            for (int j = 0; j < 4; ++j)
                acc[i][j] = __builtin_amdgcn_mfma_f32_16x16x32_f16(af[i], bf[j], acc[i][j], 0, 0, 0);
    }

#pragma unroll
    for (int i = 0; i < 4; ++i)
#pragma unroll
        for (int j = 0; j < 4; ++j) {
            int col = n0 + wc + j * 16 + r;
            float bv = bias[col];
#pragma unroll
            for (int v = 0; v < 4; ++v) {
                int rowg = m0 + wr + i * 16 + kg * 4 + v;
                C[(size_t)rowg * N + col] = acc[i][j][v] + bv;
            }
        }
}

// ---------------- LSTM recurrence: one WG (512 thr, 8 waves) per batch row ----------------
// U CU-resident: 24 chunks pinned in registers (per column), 8 chunks in LDS.
// amdgpu_waves_per_eu(2,2): LDS (132.5 KB) already limits to 1 WG/CU = 2 waves/SIMD,
// so this costs nothing and raises the VGPR budget to 256 (kills the spill of ur0/ur1).

__global__ __launch_bounds__(512)
__attribute__((amdgpu_waves_per_eu(2, 2)))
void lstm_rec4_kernel(
    const float* __restrict__ xz,     // [B*T][1024], bias included
    const uint4* __restrict__ Upk,    // [32][1024]
    ushort_t* __restrict__ out_h16,
    float* __restrict__ out_f32,
    int T)
{
    __shared__ uint4 Ulds[LCH * 1024];        // 128 KB
    __shared__ float zbuf[G4];                // 4 KB
    __shared__ uint_t h32[HID / 2];           // 512 B

    int tid = threadIdx.x;        // 0..511
    int b = blockIdx.x;
    int g0 = tid;
    int g1 = tid + 512;

    // stage LDS-held U chunks (j = RCH..31)
#pragma unroll
    for (int s = 0; s < 16; ++s) {
        int idx = s * 512 + tid;
        Ulds[idx] = Upk[RCH * 1024 + idx];
    }
    if (tid < HID / 2) h32[tid] = 0;

    // preload register-held U chunks, then pin them (no rematerialization)
    uint4 ur0[RCH], ur1[RCH];
#pragma unroll
    for (int j = 0; j < RCH; ++j) {
        ur0[j] = Upk[j * 1024 + g0];
        ur1[j] = Upk[j * 1024 + g1];
    }
#pragma unroll
    for (int j = 0; j < RCH; ++j) {
        PIN4(ur0[j]);
        PIN4(ur1[j]);
    }
    float c = 0.f;
    __syncthreads();

    const uint4* hp4 = (const uint4*)h32;

    // prefetch xz for t=0
    const float* xz_b = xz + (size_t)b * T * G4;
    float xzp0 = xz_b[g0];
    float xzp1 = xz_b[g1];

    for (int t = 0; t < T; ++t) {
        float z0a = xzp0, z1a = xzp1;
        float z0b = 0.f, z1b = 0.f;

        // prefetch next step's xz early — latency hides under the dot loop
        if (t + 1 < T) {
            const float* xzn = xz_b + (size_t)(t + 1) * G4;
            xzp0 = xzn[g0];
            xzp1 = xzn[g1];
        }

#pragma unroll
        for (int j = 0; j < RCH; j += 2) {
            uint4 h0 = hp4[j];
            uint4 h1 = hp4[j + 1];
            dot8(z0a, ur0[j], h0);
            dot8(z1a, ur1[j], h0);
            dot8(z0b, ur0[j + 1], h1);
            dot8(z1b, ur1[j + 1], h1);
        }
#pragma unroll
        for (int j = 0; j < LCH; j += 2) {
            uint4 h0 = hp4[RCH + j];
            uint4 h1 = hp4[RCH + j + 1];
            uint4 u00 = Ulds[j * 1024 + g0];
            uint4 u01 = Ulds[j * 1024 + g1];
            uint4 u10 = Ulds[(j + 1) * 1024 + g0];
            uint4 u11 = Ulds[(j + 1) * 1024 + g1];
            dot8(z0a, u00, h0);
            dot8(z1a, u01, h0);
            dot8(z0b, u10, h1);
            dot8(z1b, u11, h1);
        }
        zbuf[g0] = z0a + z0b;
        zbuf[g1] = z1a + z1b;
        __syncthreads();

        if (tid < HID) {
            float iv = zbuf[tid];
            float fv = zbuf[tid + HID];
            float gv = zbuf[tid + 2 * HID];
            float ov = zbuf[tid + 3 * HID];
            c = sig_(fv) * c + sig_(iv) * tanh_(gv);
            float h = sig_(ov) * tanh_(c);
            size_t oi = ((size_t)b * T + t) * HID + tid;
            if (out_f32) out_f32[oi] = h;
            else out_h16[oi] = f16b(h);
            ((ushort_t*)h32)[tid] = f16b(h);
        }
        __syncthreads();
    }
}

// ---------------- launch ----------------

extern "C" void kernel_launch(void* const* d_in, const int* in_sizes, int n_in,
                              void* d_out, int out_size, void* d_ws, size_t ws_size,
                              hipStream_t stream) {
    const float* x  = (const float*)d_in[0];
    const float* W0 = (const float*)d_in[1];
    const float* U0 = (const float*)d_in[2];
    const float* b0 = (const float*)d_in[3];
    const float* W1 = (const float*)d_in[4];
    const float* U1 = (const float*)d_in[5];
    const float* b1 = (const float*)d_in[6];
    float* out = (float*)d_out;

    const size_t M = (size_t)BATCH * SEQT;   // 32768

    char* ws = (char*)d_ws;
    ushort_t* xf16  = (ushort_t*)(ws);                        // 16 MB
    ushort_t* y1f16 = (ushort_t*)(ws + (16u << 20));          // 16 MB
    ushort_t* Wt0   = (ushort_t*)(ws + (32u << 20));          // 0.5 MB
    ushort_t* Wt1   = (ushort_t*)(ws + (32u << 20) + 524288); // 0.5 MB
    uint4*    Upk0  = (uint4*)   (ws + (33u << 20));          // 0.5 MB
    uint4*    Upk1  = (uint4*)   (ws + (33u << 20) + 524288); // 0.5 MB
    float*    xz    = (float*)   (ws + (34u << 20));          // 128 MB

    {
        int n4 = (int)(M * DIN / 4);
        cvt_x_kernel<<<dim3((n4 + 255) / 256), dim3(256), 0, stream>>>(x, xf16, n4);
        prep_wt_kernel<<<dim3(1024), dim3(256), 0, stream>>>(W0, Wt0);
        prep_wt_kernel<<<dim3(1024), dim3(256), 0, stream>>>(W1, Wt1);
        prep_upk_kernel<<<dim3(128), dim3(256), 0, stream>>>(U0, Upk0);
        prep_upk_kernel<<<dim3(128), dim3(256), 0, stream>>>(U1, Upk1);
    }

    // layer 1
    gemm_f16_kernel<<<dim3((int)(M / 128) * 8), dim3(256), 0, stream>>>(xf16, Wt0, b0, xz, (int)M);
    lstm_rec4_kernel<<<dim3(BATCH), dim3(512), 0, stream>>>(xz, Upk0, y1f16, nullptr, SEQT);

    // layer 2
    gemm_f16_kernel<<<dim3((int)(M / 128) * 8), dim3(256), 0, stream>>>(y1f16, Wt1, b1, xz, (int)M);
    lstm_rec4_kernel<<<dim3(BATCH), dim3(512), 0, stream>>>(xz, Upk1, nullptr, out, SEQT);
}

// Round 6
// 2156.385 us; speedup vs baseline: 1.0360x; 1.0360x over previous
//
#include <hip/hip_runtime.h>

typedef unsigned short ushort_t;
typedef unsigned int uint_t;

using f16x8 = __attribute__((ext_vector_type(8))) _Float16;
using f16x2 = __attribute__((ext_vector_type(2))) _Float16;
using f32x4 = __attribute__((ext_vector_type(4))) float;
using u32x4 = __attribute__((ext_vector_type(4))) unsigned int;

#define BATCH 64
#define SEQT 512
#define DIN 256
#define HID 256
#define G4 1024   // 4*HID

static __device__ __forceinline__ ushort_t f16b(float x) {
    return __builtin_bit_cast(ushort_t, (_Float16)x);
}
static __device__ __forceinline__ uint_t pk2(float a, float b) {
    return (uint_t)f16b(a) | ((uint_t)f16b(b) << 16);
}
static __device__ __forceinline__ float sig_(float x) {
    return 1.f / (1.f + __expf(-x));
}
static __device__ __forceinline__ float tanh_(float x) {
    float e = __expf(2.f * x);
    return (e - 1.f) / (e + 1.f);
}

// opaque pins: force residency in AGPR / VGPR (no remat, no spill rationale)
#define PINA(x) asm volatile("" : "+a"(x))
#define PINV(x) asm volatile("" : "+v"(x))

static __device__ __forceinline__ f16x8 asf16(u32x4 v) {
    return __builtin_bit_cast(f16x8, v);
}

// ---------------- prep kernels ----------------

__global__ void cvt_x_kernel(const float* __restrict__ in, ushort_t* __restrict__ out, int n4) {
    int i = blockIdx.x * blockDim.x + threadIdx.x;
    if (i < n4) {
        float4 v = ((const float4*)in)[i];
        ushort4 o;
        o.x = f16b(v.x); o.y = f16b(v.y); o.z = f16b(v.z); o.w = f16b(v.w);
        ((ushort4*)out)[i] = o;
    }
}

// W [256][1024] f32 -> Wt [1024][256] f16 bits (transpose)
__global__ void prep_wt_kernel(const float* __restrict__ W, ushort_t* __restrict__ Wt) {
    int tid = blockIdx.x * blockDim.x + threadIdx.x;
    int k = tid >> 10;
    int n = tid & 1023;
    Wt[n * DIN + k] = f16b(W[tid]);
}

// U [256][1024] f32 -> Upk [32][1024] uint4; Upk[j][g] = f16 pairs for k=8j..8j+7, col g
__global__ void prep_upk_kernel(const float* __restrict__ U, uint4* __restrict__ Upk) {
    int tid = blockIdx.x * blockDim.x + threadIdx.x;
    int j = tid >> 10;
    int g = tid & 1023;
    uint4 o;
    uint_t* op = &o.x;
#pragma unroll
    for (int q = 0; q < 4; ++q) {
        float a = U[(8 * j + 2 * q) * G4 + g];
        float b = U[(8 * j + 2 * q + 1) * G4 + g];
        op[q] = pk2(a, b);
    }
    Upk[tid] = o;
}

// ---------------- GEMM (unchanged, passing) ----------------

#define GSTRIDE 40

__global__ __launch_bounds__(256) void gemm_f16_kernel(
    const ushort_t* __restrict__ A,
    const ushort_t* __restrict__ Bt,
    const float* __restrict__ bias,
    float* __restrict__ C,
    int M)
{
    const int K = DIN, N = G4;
    __shared__ ushort_t As[128 * GSTRIDE];
    __shared__ ushort_t Bs[128 * GSTRIDE];
    int tid = threadIdx.x;
    int bx = blockIdx.x & 7;
    int by = blockIdx.x >> 3;
    int m0 = by * 128, n0 = bx * 128;
    int w = tid >> 6, lane = tid & 63;
    int wr = (w >> 1) * 64, wc = (w & 1) * 64;
    int r = lane & 15, kg = lane >> 4;

    f32x4 acc[4][4];
#pragma unroll
    for (int i = 0; i < 4; ++i)
#pragma unroll
        for (int j = 0; j < 4; ++j)
            acc[i][j] = f32x4{0.f, 0.f, 0.f, 0.f};

    for (int kt = 0; kt < K; kt += 32) {
        __syncthreads();
#pragma unroll
        for (int s = 0; s < 2; ++s) {
            int chunk = tid + s * 256;
            int row = chunk >> 2;
            int ko = (chunk & 3) * 8;
            uint4 va = *(const uint4*)(A + (size_t)(m0 + row) * K + kt + ko);
            *(uint4*)(&As[row * GSTRIDE + ko]) = va;
            uint4 vb = *(const uint4*)(Bt + (size_t)(n0 + row) * K + kt + ko);
            *(uint4*)(&Bs[row * GSTRIDE + ko]) = vb;
        }
        __syncthreads();
        f16x8 af[4], bf[4];
#pragma unroll
        for (int i = 0; i < 4; ++i) {
            af[i] = *(const f16x8*)(&As[(wr + i * 16 + r) * GSTRIDE + kg * 8]);
            bf[i] = *(const f16x8*)(&Bs[(wc + i * 16 + r) * GSTRIDE + kg * 8]);
        }
#pragma unroll
        for (int i = 0; i < 4; ++i)
#pragma unroll
            for (int j = 0; j < 4; ++j)
                acc[i][j] = __builtin_amdgcn_mfma_f32_16x16x32_f16(af[i], bf[j], acc[i][j], 0, 0, 0);
    }

#pragma unroll
    for (int i = 0; i < 4; ++i)
#pragma unroll
        for (int j = 0; j < 4; ++j) {
            int col = n0 + wc + j * 16 + r;
            float bv = bias[col];
#pragma unroll
            for (int v = 0; v < 4; ++v) {
                int rowg = m0 + wr + i * 16 + kg * 4 + v;
                C[(size_t)rowg * N + col] = acc[i][j][v] + bv;
            }
        }
}

// ---------------- LSTM recurrence via MFMA (builtin, hazard-safe) ----------------
// 1 WG (256 thr, 4 waves) per batch row. Wave w owns n-tiles 16w..16w+15.
// z = h @ U via builtin MFMA; h replicated into all A rows -> every C row = z.
// U B-frags: kt0-3 pinned to AGPR (256), kt4-5 pinned to VGPR (128), kt6-7 in LDS.

__global__ __launch_bounds__(256)
__attribute__((amdgpu_waves_per_eu(1, 1)))
void lstm_mfma2_kernel(
    const float* __restrict__ xz,     // [B*T][1024], bias included
    const uint4* __restrict__ Upk,    // [32][1024] uint4
    ushort_t* __restrict__ out_h16,
    float* __restrict__ out_f32,
    int T)
{
    __shared__ __align__(16) u32x4 Uld[4][2][16][64];   // 128 KB: [wave][kt-6][ntl][lane]
    __shared__ __align__(16) float zx[2][G4];           // 8 KB xz staging (ping-pong)
    __shared__ __align__(16) float zex[16][68];         // 4.25 KB z exchange (bank-padded)
    __shared__ __align__(16) ushort_t h16[HID];         // 512 B

    const int tid = threadIdx.x;
    const int w = tid >> 6;          // wave 0..3
    const int l = tid & 63;          // lane
    const int lg = l >> 4;           // k-chunk group 0..3
    const int lr = l & 15;           // col-in-tile
    const int b = blockIdx.x;
    const u32x4* Upk4 = (const u32x4*)Upk;

    // ---- preload U fragments ----
    u32x4 ua[64];   // kt 0..3  -> AGPR
    u32x4 uv[32];   // kt 4..5  -> VGPR
#pragma unroll
    for (int ntl = 0; ntl < 16; ++ntl) {
        int col = (w * 16 + ntl) * 16 + lr;
#pragma unroll
        for (int kt = 0; kt < 4; ++kt)
            ua[ntl * 4 + kt] = Upk4[(kt * 4 + lg) * 1024 + col];
#pragma unroll
        for (int k2 = 0; k2 < 2; ++k2)
            uv[ntl * 2 + k2] = Upk4[((4 + k2) * 4 + lg) * 1024 + col];
    }
#pragma unroll
    for (int i = 0; i < 64; ++i) PINA(ua[i]);
#pragma unroll
    for (int i = 0; i < 32; ++i) PINV(uv[i]);

    // ---- stage kt6-7 into LDS (each wave its own tiles) ----
#pragma unroll
    for (int k2 = 0; k2 < 2; ++k2)
#pragma unroll
        for (int ntl = 0; ntl < 16; ++ntl) {
            int col = (w * 16 + ntl) * 16 + lr;
            Uld[w][k2][ntl][l] = Upk4[((6 + k2) * 4 + lg) * 1024 + col];
        }

    h16[tid] = 0;
    // stage xz[t=0]
    const float* xz_b = xz + (size_t)b * T * G4;
    {
        float4 x0 = ((const float4*)xz_b)[tid];
        *(float4*)&zx[0][tid * 4] = x0;
    }
    float c = 0.f;
    __syncthreads();

    for (int t = 0; t < T; ++t) {
        const int cur = t & 1, nxt = cur ^ 1;

        // prefetch next xz into regs (hides under MFMAs)
        float4 xn = float4{0.f, 0.f, 0.f, 0.f};
        if (t + 1 < T) xn = ((const float4*)(xz_b + (size_t)(t + 1) * G4))[tid];

        // A fragments: h chunk (replicated across rows; row-mapping immaterial)
        f16x8 af[8];
#pragma unroll
        for (int kt = 0; kt < 8; ++kt)
            af[kt] = *(const f16x8*)((const char*)h16 + kt * 64 + lg * 16);

#pragma unroll
        for (int half = 0; half < 2; ++half) {
            f32x4 acc[8];
#pragma unroll
            for (int i = 0; i < 8; ++i) acc[i] = f32x4{0.f, 0.f, 0.f, 0.f};

#pragma unroll
            for (int i = 0; i < 8; ++i) {
                int ntl = half * 8 + i;
#pragma unroll
                for (int kt = 0; kt < 4; ++kt)
                    acc[i] = __builtin_amdgcn_mfma_f32_16x16x32_f16(
                        af[kt], asf16(ua[ntl * 4 + kt]), acc[i], 0, 0, 0);
#pragma unroll
                for (int k2 = 0; k2 < 2; ++k2)
                    acc[i] = __builtin_amdgcn_mfma_f32_16x16x32_f16(
                        af[4 + k2], asf16(uv[ntl * 2 + k2]), acc[i], 0, 0, 0);
#pragma unroll
                for (int k2 = 0; k2 < 2; ++k2) {
                    u32x4 ub = Uld[w][k2][ntl][l];
                    acc[i] = __builtin_amdgcn_mfma_f32_16x16x32_f16(
                        af[6 + k2], asf16(ub), acc[i], 0, 0, 0);
                }
            }
            // extract z (col = lane&15 of each n-tile; all C rows identical)
            if (l < 16) {
                int ntb = w * 16 + half * 8;
                f32x4 p0, p1;
                p0[0] = acc[0][0]; p0[1] = acc[1][0]; p0[2] = acc[2][0]; p0[3] = acc[3][0];
                p1[0] = acc[4][0]; p1[1] = acc[5][0]; p1[2] = acc[6][0]; p1[3] = acc[7][0];
                *(f32x4*)&zex[l][ntb] = p0;
                *(f32x4*)&zex[l][ntb + 4] = p1;
            }
        }

        // stage next xz
        *(float4*)&zx[nxt][tid * 4] = xn;
        __syncthreads();

        // gates: thread k owns column k
        {
            int k = tid;
            int r = k & 15, q = k >> 4;
            float iv = zex[r][q]      + zx[cur][k];
            float fv = zex[r][q + 16] + zx[cur][k + 256];
            float gv = zex[r][q + 32] + zx[cur][k + 512];
            float ov = zex[r][q + 48] + zx[cur][k + 768];
            c = sig_(fv) * c + sig_(iv) * tanh_(gv);
            float h = sig_(ov) * tanh_(c);
            size_t oi = ((size_t)b * T + t) * HID + k;
            if (out_f32) out_f32[oi] = h;
            else out_h16[oi] = f16b(h);
            h16[k] = f16b(h);
        }
        __syncthreads();
    }
}

// ---------------- launch ----------------

extern "C" void kernel_launch(void* const* d_in, const int* in_sizes, int n_in,
                              void* d_out, int out_size, void* d_ws, size_t ws_size,
                              hipStream_t stream) {
    const float* x  = (const float*)d_in[0];
    const float* W0 = (const float*)d_in[1];
    const float* U0 = (const float*)d_in[2];
    const float* b0 = (const float*)d_in[3];
    const float* W1 = (const float*)d_in[4];
    const float* U1 = (const float*)d_in[5];
    const float* b1 = (const float*)d_in[6];
    float* out = (float*)d_out;

    const size_t M = (size_t)BATCH * SEQT;   // 32768

    char* ws = (char*)d_ws;
    ushort_t* xf16  = (ushort_t*)(ws);                        // 16 MB
    ushort_t* y1f16 = (ushort_t*)(ws + (16u << 20));          // 16 MB
    ushort_t* Wt0   = (ushort_t*)(ws + (32u << 20));          // 0.5 MB
    ushort_t* Wt1   = (ushort_t*)(ws + (32u << 20) + 524288); // 0.5 MB
    uint4*    Upk0  = (uint4*)   (ws + (33u << 20));          // 0.5 MB
    uint4*    Upk1  = (uint4*)   (ws + (33u << 20) + 524288); // 0.5 MB
    float*    xz    = (float*)   (ws + (34u << 20));          // 128 MB

    {
        int n4 = (int)(M * DIN / 4);
        cvt_x_kernel<<<dim3((n4 + 255) / 256), dim3(256), 0, stream>>>(x, xf16, n4);
        prep_wt_kernel<<<dim3(1024), dim3(256), 0, stream>>>(W0, Wt0);
        prep_wt_kernel<<<dim3(1024), dim3(256), 0, stream>>>(W1, Wt1);
        prep_upk_kernel<<<dim3(128), dim3(256), 0, stream>>>(U0, Upk0);
        prep_upk_kernel<<<dim3(128), dim3(256), 0, stream>>>(U1, Upk1);
    }

    // layer 1
    gemm_f16_kernel<<<dim3((int)(M / 128) * 8), dim3(256), 0, stream>>>(xf16, Wt0, b0, xz, (int)M);
    lstm_mfma2_kernel<<<dim3(BATCH), dim3(256), 0, stream>>>(xz, Upk0, y1f16, nullptr, SEQT);

    // layer 2
    gemm_f16_kernel<<<dim3((int)(M / 128) * 8), dim3(256), 0, stream>>>(y1f16, Wt1, b1, xz, (int)M);
    lstm_mfma2_kernel<<<dim3(BATCH), dim3(256), 0, stream>>>(xz, Upk1, nullptr, out, SEQT);
}

// Round 7
// 2077.409 us; speedup vs baseline: 1.0754x; 1.0380x over previous
//
#include <hip/hip_runtime.h>

typedef unsigned short ushort_t;
typedef unsigned int uint_t;

using f16x8 = __attribute__((ext_vector_type(8))) _Float16;
using f16x2 = __attribute__((ext_vector_type(2))) _Float16;
using f32x4 = __attribute__((ext_vector_type(4))) float;
using u32x4 = __attribute__((ext_vector_type(4))) unsigned int;

#define BATCH 64
#define SEQT 512
#define DIN 256
#define HID 256
#define G4 1024   // 4*HID

static __device__ __forceinline__ ushort_t f16b(float x) {
    return __builtin_bit_cast(ushort_t, (_Float16)x);
}
static __device__ __forceinline__ uint_t pk2(float a, float b) {
    return (uint_t)f16b(a) | ((uint_t)f16b(b) << 16);
}
static __device__ __forceinline__ float sig_(float x) {
    return 1.f / (1.f + __expf(-x));
}
static __device__ __forceinline__ float tanh_(float x) {
    float e = __expf(2.f * x);
    return (e - 1.f) / (e + 1.f);
}

// opaque pins: force residency in AGPR / VGPR (no remat, no spill rationale)
#define PINA(x) asm volatile("" : "+a"(x))
#define PINV(x) asm volatile("" : "+v"(x))

static __device__ __forceinline__ f16x8 asf16(u32x4 v) {
    return __builtin_bit_cast(f16x8, v);
}

// ---------------- prep kernels ----------------

__global__ void cvt_x_kernel(const float* __restrict__ in, ushort_t* __restrict__ out, int n4) {
    int i = blockIdx.x * blockDim.x + threadIdx.x;
    if (i < n4) {
        float4 v = ((const float4*)in)[i];
        ushort4 o;
        o.x = f16b(v.x); o.y = f16b(v.y); o.z = f16b(v.z); o.w = f16b(v.w);
        ((ushort4*)out)[i] = o;
    }
}

// W [256][1024] f32 -> Wt [1024][256] f16 bits (transpose)
__global__ void prep_wt_kernel(const float* __restrict__ W, ushort_t* __restrict__ Wt) {
    int tid = blockIdx.x * blockDim.x + threadIdx.x;
    int k = tid >> 10;
    int n = tid & 1023;
    Wt[n * DIN + k] = f16b(W[tid]);
}

// U [256][1024] f32 -> Upk [32][1024] uint4; Upk[j][g] = f16 pairs for k=8j..8j+7, col g
__global__ void prep_upk_kernel(const float* __restrict__ U, uint4* __restrict__ Upk) {
    int tid = blockIdx.x * blockDim.x + threadIdx.x;
    int j = tid >> 10;
    int g = tid & 1023;
    uint4 o;
    uint_t* op = &o.x;
#pragma unroll
    for (int q = 0; q < 4; ++q) {
        float a = U[(8 * j + 2 * q) * G4 + g];
        float b = U[(8 * j + 2 * q + 1) * G4 + g];
        op[q] = pk2(a, b);
    }
    Upk[tid] = o;
}

// ---------------- GEMM (unchanged, passing) ----------------

#define GSTRIDE 40

__global__ __launch_bounds__(256) void gemm_f16_kernel(
    const ushort_t* __restrict__ A,
    const ushort_t* __restrict__ Bt,
    const float* __restrict__ bias,
    float* __restrict__ C,
    int M)
{
    const int K = DIN, N = G4;
    __shared__ ushort_t As[128 * GSTRIDE];
    __shared__ ushort_t Bs[128 * GSTRIDE];
    int tid = threadIdx.x;
    int bx = blockIdx.x & 7;
    int by = blockIdx.x >> 3;
    int m0 = by * 128, n0 = bx * 128;
    int w = tid >> 6, lane = tid & 63;
    int wr = (w >> 1) * 64, wc = (w & 1) * 64;
    int r = lane & 15, kg = lane >> 4;

    f32x4 acc[4][4];
#pragma unroll
    for (int i = 0; i < 4; ++i)
#pragma unroll
        for (int j = 0; j < 4; ++j)
            acc[i][j] = f32x4{0.f, 0.f, 0.f, 0.f};

    for (int kt = 0; kt < K; kt += 32) {
        __syncthreads();
#pragma unroll
        for (int s = 0; s < 2; ++s) {
            int chunk = tid + s * 256;
            int row = chunk >> 2;
            int ko = (chunk & 3) * 8;
            uint4 va = *(const uint4*)(A + (size_t)(m0 + row) * K + kt + ko);
            *(uint4*)(&As[row * GSTRIDE + ko]) = va;
            uint4 vb = *(const uint4*)(Bt + (size_t)(n0 + row) * K + kt + ko);
            *(uint4*)(&Bs[row * GSTRIDE + ko]) = vb;
        }
        __syncthreads();
        f16x8 af[4], bf[4];
#pragma unroll
        for (int i = 0; i < 4; ++i) {
            af[i] = *(const f16x8*)(&As[(wr + i * 16 + r) * GSTRIDE + kg * 8]);
            bf[i] = *(const f16x8*)(&Bs[(wc + i * 16 + r) * GSTRIDE + kg * 8]);
        }
#pragma unroll
        for (int i = 0; i < 4; ++i)
#pragma unroll
            for (int j = 0; j < 4; ++j)
                acc[i][j] = __builtin_amdgcn_mfma_f32_16x16x32_f16(af[i], bf[j], acc[i][j], 0, 0, 0);
    }

#pragma unroll
    for (int i = 0; i < 4; ++i)
#pragma unroll
        for (int j = 0; j < 4; ++j) {
            int col = n0 + wc + j * 16 + r;
            float bv = bias[col];
#pragma unroll
            for (int v = 0; v < 4; ++v) {
                int rowg = m0 + wr + i * 16 + kg * 4 + v;
                C[(size_t)rowg * N + col] = acc[i][j][v] + bv;
            }
        }
}

// ---------------- LSTM recurrence via MFMA, in-register gates ----------------
// 1 WG (256 thr, 4 waves) per batch row. Wave w owns, for each gate block gb,
// tiles nt = gb*16 + w*4 + ti (ti=0..3) -> cols gb*256 + w*64 + [0,64).
// So each lane (ti = lane>>4 selected) ends up with i,f,g,o for ONE h-column
// in registers: no z exchange, no lane divergence, 1 barrier/step.
// U frags: kt0-3 pinned AGPR (256), kt4-5 pinned VGPR (128), kt6-7 LDS (128KB).

__global__ __launch_bounds__(256)
__attribute__((amdgpu_waves_per_eu(1, 1)))
void lstm_mfma3_kernel(
    const float* __restrict__ xz,     // [B*T][1024], bias included
    const uint4* __restrict__ Upk,    // [32][1024] uint4
    ushort_t* __restrict__ out_h16,
    float* __restrict__ out_f32,
    int T)
{
    __shared__ __align__(16) u32x4 Uld[4][2][16][64];   // 128 KB [wave][kt-6][gb*4+ti][lane]
    __shared__ __align__(16) ushort_t h16[2][HID];      // 1 KB double-buffered h

    const int tid = threadIdx.x;
    const int w = tid >> 6;          // wave 0..3
    const int l = tid & 63;          // lane
    const int lg = l >> 4;           // lane group 0..3 (A k-group; also ti select)
    const int lr = l & 15;           // col-in-tile
    const int b = blockIdx.x;
    const u32x4* Upk4 = (const u32x4*)Upk;

    const int hcol = w * 64 + lg * 16 + lr;   // this lane's h column

    // ---- preload U fragments (col = (gb*16 + w*4 + ti)*16 + lr) ----
    u32x4 ua[64];   // [ (gb*4+ti)*4 + kt ]  kt 0..3 -> AGPR
    u32x4 uv[32];   // [ (gb*4+ti)*2 + k2 ]  kt 4..5 -> VGPR
#pragma unroll
    for (int gb = 0; gb < 4; ++gb)
#pragma unroll
        for (int ti = 0; ti < 4; ++ti) {
            int col = (gb * 16 + w * 4 + ti) * 16 + lr;
            int fi = gb * 4 + ti;
#pragma unroll
            for (int kt = 0; kt < 4; ++kt)
                ua[fi * 4 + kt] = Upk4[(kt * 4 + lg) * 1024 + col];
#pragma unroll
            for (int k2 = 0; k2 < 2; ++k2)
                uv[fi * 2 + k2] = Upk4[((4 + k2) * 4 + lg) * 1024 + col];
        }
#pragma unroll
    for (int i = 0; i < 64; ++i) PINA(ua[i]);
#pragma unroll
    for (int i = 0; i < 32; ++i) PINV(uv[i]);

    // ---- stage kt6-7 into LDS ----
#pragma unroll
    for (int gb = 0; gb < 4; ++gb)
#pragma unroll
        for (int ti = 0; ti < 4; ++ti) {
            int col = (gb * 16 + w * 4 + ti) * 16 + lr;
            int fi = gb * 4 + ti;
#pragma unroll
            for (int k2 = 0; k2 < 2; ++k2)
                Uld[w][k2][fi][l] = Upk4[((6 + k2) * 4 + lg) * 1024 + col];
        }

    h16[0][tid] = 0;

    // xz for t=0 (per-lane, 4 gate columns)
    const float* xz_b = xz + (size_t)b * T * G4;
    float xzc[4];
#pragma unroll
    for (int gb = 0; gb < 4; ++gb) xzc[gb] = xz_b[gb * 256 + hcol];

    float c = 0.f;
    size_t obase = (size_t)b * T * HID + hcol;
    __syncthreads();

    for (int t = 0; t < T; ++t) {
        const int cur = t & 1, nxt = cur ^ 1;

        // A fragments: h chunk (row-replicated; only col mapping matters)
        f16x8 af[8];
#pragma unroll
        for (int kt = 0; kt < 8; ++kt)
            af[kt] = *(const f16x8*)((const char*)h16[cur] + kt * 64 + lg * 16);

        // prefetch next xz into regs (hides under MFMAs)
        float xzn[4];
        {
            const float* xztn = xz_b + (size_t)((t + 1 < T) ? (t + 1) : t) * G4;
#pragma unroll
            for (int gb = 0; gb < 4; ++gb) xzn[gb] = xztn[gb * 256 + hcol];
        }

        float zg[4];
#pragma unroll
        for (int gb = 0; gb < 4; ++gb) {
            // 8 concurrent chains of 4 MFMAs (accA: kt0-3, accB: kt4-7)
            f32x4 accA[4], accB[4];
#pragma unroll
            for (int ti = 0; ti < 4; ++ti) {
                accA[ti] = f32x4{0.f, 0.f, 0.f, 0.f};
                accB[ti] = f32x4{0.f, 0.f, 0.f, 0.f};
            }
#pragma unroll
            for (int ti = 0; ti < 4; ++ti) {
                int fi = gb * 4 + ti;
#pragma unroll
                for (int kt = 0; kt < 4; ++kt)
                    accA[ti] = __builtin_amdgcn_mfma_f32_16x16x32_f16(
                        af[kt], asf16(ua[fi * 4 + kt]), accA[ti], 0, 0, 0);
#pragma unroll
                for (int k2 = 0; k2 < 2; ++k2)
                    accB[ti] = __builtin_amdgcn_mfma_f32_16x16x32_f16(
                        af[4 + k2], asf16(uv[fi * 2 + k2]), accB[ti], 0, 0, 0);
#pragma unroll
                for (int k2 = 0; k2 < 2; ++k2) {
                    u32x4 ub = Uld[w][k2][fi][l];
                    accB[ti] = __builtin_amdgcn_mfma_f32_16x16x32_f16(
                        af[6 + k2], asf16(ub), accB[ti], 0, 0, 0);
                }
            }
            // lane's column uses ti = lg (compile-time select chain)
            float za = (lg == 0) ? accA[0][0] : (lg == 1) ? accA[1][0]
                     : (lg == 2) ? accA[2][0] : accA[3][0];
            float zb = (lg == 0) ? accB[0][0] : (lg == 1) ? accB[1][0]
                     : (lg == 2) ? accB[2][0] : accB[3][0];
            zg[gb] = za + zb + xzc[gb];
        }

        // gates fully in-register (all 64 lanes active)
        c = sig_(zg[1]) * c + sig_(zg[0]) * tanh_(zg[2]);
        float h = sig_(zg[3]) * tanh_(c);

        h16[nxt][hcol] = f16b(h);
        if (out_f32) out_f32[obase] = h;
        else out_h16[obase] = f16b(h);
        obase += HID;

#pragma unroll
        for (int gb = 0; gb < 4; ++gb) xzc[gb] = xzn[gb];

        __syncthreads();
    }
}

// ---------------- launch ----------------

extern "C" void kernel_launch(void* const* d_in, const int* in_sizes, int n_in,
                              void* d_out, int out_size, void* d_ws, size_t ws_size,
                              hipStream_t stream) {
    const float* x  = (const float*)d_in[0];
    const float* W0 = (const float*)d_in[1];
    const float* U0 = (const float*)d_in[2];
    const float* b0 = (const float*)d_in[3];
    const float* W1 = (const float*)d_in[4];
    const float* U1 = (const float*)d_in[5];
    const float* b1 = (const float*)d_in[6];
    float* out = (float*)d_out;

    const size_t M = (size_t)BATCH * SEQT;   // 32768

    char* ws = (char*)d_ws;
    ushort_t* xf16  = (ushort_t*)(ws);                        // 16 MB
    ushort_t* y1f16 = (ushort_t*)(ws + (16u << 20));          // 16 MB
    ushort_t* Wt0   = (ushort_t*)(ws + (32u << 20));          // 0.5 MB
    ushort_t* Wt1   = (ushort_t*)(ws + (32u << 20) + 524288); // 0.5 MB
    uint4*    Upk0  = (uint4*)   (ws + (33u << 20));          // 0.5 MB
    uint4*    Upk1  = (uint4*)   (ws + (33u << 20) + 524288); // 0.5 MB
    float*    xz    = (float*)   (ws + (34u << 20));          // 128 MB

    {
        int n4 = (int)(M * DIN / 4);
        cvt_x_kernel<<<dim3((n4 + 255) / 256), dim3(256), 0, stream>>>(x, xf16, n4);
        prep_wt_kernel<<<dim3(1024), dim3(256), 0, stream>>>(W0, Wt0);
        prep_wt_kernel<<<dim3(1024), dim3(256), 0, stream>>>(W1, Wt1);
        prep_upk_kernel<<<dim3(128), dim3(256), 0, stream>>>(U0, Upk0);
        prep_upk_kernel<<<dim3(128), dim3(256), 0, stream>>>(U1, Upk1);
    }

    // layer 1
    gemm_f16_kernel<<<dim3((int)(M / 128) * 8), dim3(256), 0, stream>>>(xf16, Wt0, b0, xz, (int)M);
    lstm_mfma3_kernel<<<dim3(BATCH), dim3(256), 0, stream>>>(xz, Upk0, y1f16, nullptr, SEQT);

    // layer 2
    gemm_f16_kernel<<<dim3((int)(M / 128) * 8), dim3(256), 0, stream>>>(y1f16, Wt1, b1, xz, (int)M);
    lstm_mfma3_kernel<<<dim3(BATCH), dim3(256), 0, stream>>>(xz, Upk1, nullptr, out, SEQT);
}